// Round 1
// baseline (189.801 us; speedup 1.0000x reference)
//
#include <hip/hip_runtime.h>
#include <math.h>

#define NLIG 512
#define NPROT 2048
#define NTOT 2560
#define LFE 16
#define PFE 21
#define JFE 16
#define HME 16
#define DD 17   // JF+1

// ws layout in floats
#define B_OFF   0          // NTOT*16 = 40960
#define PB_OFF  40960      // NTOT*4  = 10240 (float4: x,y,z,batch-as-int)
#define A_OFF   51200      // NLIG*16 = 8192  (a_i + be)
#define H_OFF   59392      // NLIG*17 = 8704
#define AGG_OFF 68096      // NLIG*16 = 8192
#define TR_OFF  76288      // NLIG*4  = 2048
// total 78336 floats = 313,344 bytes of ws

__device__ __forceinline__ float silu_f(float x) {
    return x / (1.0f + __expf(-x));
}

__global__ __launch_bounds__(256) void encode_kernel(
    const float* __restrict__ xl, const float* __restrict__ xp,
    const float* __restrict__ posl, const float* __restrict__ posp,
    const float* __restrict__ t,
    const int* __restrict__ bl, const int* __restrict__ bp,
    const int* __restrict__ lmask,
    const float* __restrict__ aW1, const float* __restrict__ ab1,
    const float* __restrict__ aW2, const float* __restrict__ ab2,
    const float* __restrict__ fW1, const float* __restrict__ fb1,
    const float* __restrict__ fW2, const float* __restrict__ fb2,
    const float* __restrict__ rW1, const float* __restrict__ rb1,
    const float* __restrict__ rW2, const float* __restrict__ rb2,
    const float* __restrict__ We, const float* __restrict__ be,
    float* __restrict__ ws)
{
    int i = blockIdx.x * 256 + threadIdx.x;
    if (i >= NTOT) return;

    float h[DD];
    if (i < NLIG) {
        float x[LFE];
        #pragma unroll
        for (int k = 0; k < LFE; ++k) x[k] = xl[i * LFE + k];
        bool am = (lmask[i] != 0);
        const float* W1 = am ? aW1 : fW1;
        const float* b1 = am ? ab1 : fb1;
        const float* W2 = am ? aW2 : fW2;
        const float* b2 = am ? ab2 : fb2;
        float hid[2 * LFE];
        #pragma unroll
        for (int c = 0; c < 2 * LFE; ++c) {
            float s = b1[c];
            #pragma unroll
            for (int k = 0; k < LFE; ++k) s += x[k] * W1[k * (2 * LFE) + c];
            hid[c] = silu_f(s);
        }
        #pragma unroll
        for (int o = 0; o < JFE; ++o) {
            float s = b2[o];
            #pragma unroll
            for (int c = 0; c < 2 * LFE; ++c) s += hid[c] * W2[c * JFE + o];
            h[o] = s;
        }
    } else {
        int ip = i - NLIG;
        float x[PFE];
        #pragma unroll
        for (int k = 0; k < PFE; ++k) x[k] = xp[ip * PFE + k];
        float hid[2 * PFE];
        #pragma unroll
        for (int c = 0; c < 2 * PFE; ++c) {
            float s = rb1[c];
            #pragma unroll
            for (int k = 0; k < PFE; ++k) s += x[k] * rW1[k * (2 * PFE) + c];
            hid[c] = silu_f(s);
        }
        #pragma unroll
        for (int o = 0; o < JFE; ++o) {
            float s = rb2[o];
            #pragma unroll
            for (int c = 0; c < 2 * PFE; ++c) s += hid[c] * rW2[c * JFE + o];
            h[o] = s;
        }
    }
    h[DD - 1] = t[0];

    // b_j = h . We[D:2D]  (all nodes)
    #pragma unroll
    for (int m = 0; m < HME; ++m) {
        float s = 0.0f;
        #pragma unroll
        for (int k = 0; k < DD; ++k) s += h[k] * We[(DD + k) * HME + m];
        ws[B_OFF + i * HME + m] = s;
    }

    // packed pos + batch
    float px, py, pz; int bt;
    if (i < NLIG) { px = posl[i*3]; py = posl[i*3+1]; pz = posl[i*3+2]; bt = bl[i]; }
    else { int ip = i - NLIG; px = posp[ip*3]; py = posp[ip*3+1]; pz = posp[ip*3+2]; bt = bp[ip]; }
    ((float4*)(ws + PB_OFF))[i] = make_float4(px, py, pz, __int_as_float(bt));

    if (i < NLIG) {
        // a_i = h . We[:D] + be   (ligand rows are the only i we need)
        #pragma unroll
        for (int m = 0; m < HME; ++m) {
            float s = be[m];
            #pragma unroll
            for (int k = 0; k < DD; ++k) s += h[k] * We[k * HME + m];
            ws[A_OFF + i * HME + m] = s;
        }
        #pragma unroll
        for (int k = 0; k < DD; ++k) ws[H_OFF + i * DD + k] = h[k];
    }
}

// one wave (64 lanes) per ligand node i; lanes stride over all j
__global__ __launch_bounds__(256) void pair_kernel(
    const float* __restrict__ We, const float* __restrict__ Wx,
    const float* __restrict__ bx, float* __restrict__ ws)
{
    int gtid = blockIdx.x * 256 + threadIdx.x;
    int i = gtid >> 6;
    int lane = threadIdx.x & 63;
    if (i >= NLIG) return;

    const float* Bv = ws + B_OFF;
    const float4* PB = (const float4*)(ws + PB_OFF);
    float4 pi = PB[i];
    int bi = __float_as_int(pi.w);

    float Ai[HME], w2[HME], wx[HME];
    #pragma unroll
    for (int m = 0; m < HME; ++m) {
        Ai[m] = ws[A_OFF + i * HME + m];
        w2[m] = We[2 * DD * HME + m];   // row 2D of We (the d2 coefficient)
        wx[m] = Wx[m];
    }
    float bxv = bx[0];

    float agg[HME];
    #pragma unroll
    for (int m = 0; m < HME; ++m) agg[m] = 0.0f;
    float tx = 0.0f, ty = 0.0f, tz = 0.0f;

    for (int j = lane; j < NTOT; j += 64) {
        float4 pj = PB[j];
        if (__float_as_int(pj.w) != bi) continue;   // batch blocks are 64-aligned -> wave-uniform
        float dx = pi.x - pj.x, dy = pi.y - pj.y, dz = pi.z - pj.z;
        float d2 = dx * dx + dy * dy + dz * dz;
        if (d2 >= 25.0f) continue;
        const float4* bj4 = (const float4*)(Bv + j * HME);
        float bj[HME];
        *(float4*)(bj + 0)  = bj4[0];
        *(float4*)(bj + 4)  = bj4[1];
        *(float4*)(bj + 8)  = bj4[2];
        *(float4*)(bj + 12) = bj4[3];
        float e = bxv;
        #pragma unroll
        for (int m = 0; m < HME; ++m) {
            float pre = Ai[m] + bj[m] + d2 * w2[m];
            float s = silu_f(pre);
            agg[m] += s;
            e += s * wx[m];
        }
        tx += dx * e; ty += dy * e; tz += dz * e;
    }

    // wave reduction of agg[16] + trans[3]
    #pragma unroll
    for (int off = 32; off >= 1; off >>= 1) {
        #pragma unroll
        for (int m = 0; m < HME; ++m) agg[m] += __shfl_down(agg[m], off, 64);
        tx += __shfl_down(tx, off, 64);
        ty += __shfl_down(ty, off, 64);
        tz += __shfl_down(tz, off, 64);
    }
    if (lane == 0) {
        #pragma unroll
        for (int m = 0; m < HME; ++m) ws[AGG_OFF + i * HME + m] = agg[m];
        ws[TR_OFF + i * 4 + 0] = tx;
        ws[TR_OFF + i * 4 + 1] = ty;
        ws[TR_OFF + i * 4 + 2] = tz;
    }
}

__global__ __launch_bounds__(256) void decode_kernel(
    const int* __restrict__ lmask,
    const float* __restrict__ Wh, const float* __restrict__ bh,
    const float* __restrict__ dW1, const float* __restrict__ db1,
    const float* __restrict__ dW2, const float* __restrict__ db2,
    const float* __restrict__ ws, float* __restrict__ out)
{
    int i = blockIdx.x * 256 + threadIdx.x;
    if (i >= NLIG) return;
    bool msk = (lmask[i] != 0);

    float hfull[DD], g[HME];
    #pragma unroll
    for (int k = 0; k < DD; ++k) hfull[k] = ws[H_OFF + i * DD + k];
    #pragma unroll
    for (int k = 0; k < HME; ++k) g[k] = ws[AGG_OFF + i * HME + k];

    float ho[JFE];
    #pragma unroll
    for (int c = 0; c < JFE; ++c) {
        float s = bh[c];
        #pragma unroll
        for (int k = 0; k < DD; ++k) s += hfull[k] * Wh[k * JFE + c];
        #pragma unroll
        for (int k = 0; k < HME; ++k) s += g[k] * Wh[(DD + k) * JFE + c];
        ho[c] = s;
    }
    float hid[2 * LFE];
    #pragma unroll
    for (int c = 0; c < 2 * LFE; ++c) {
        float s = db1[c];
        #pragma unroll
        for (int k = 0; k < JFE; ++k) s += ho[k] * dW1[k * (2 * LFE) + c];
        hid[c] = silu_f(s);
    }
    #pragma unroll
    for (int o = 0; o < LFE; ++o) {
        float s = db2[o];
        #pragma unroll
        for (int c = 0; c < 2 * LFE; ++c) s += hid[c] * dW2[c * LFE + o];
        out[i * 19 + o] = msk ? s : 0.0f;
    }
    out[i * 19 + 16] = msk ? ws[TR_OFF + i * 4 + 0] : 0.0f;
    out[i * 19 + 17] = msk ? ws[TR_OFF + i * 4 + 1] : 0.0f;
    out[i * 19 + 18] = msk ? ws[TR_OFF + i * 4 + 2] : 0.0f;
}

extern "C" void kernel_launch(void* const* d_in, const int* in_sizes, int n_in,
                              void* d_out, int out_size, void* d_ws, size_t ws_size,
                              hipStream_t stream) {
    const float* xl   = (const float*)d_in[0];
    const float* xp   = (const float*)d_in[1];
    const float* posl = (const float*)d_in[2];
    const float* posp = (const float*)d_in[3];
    const float* t    = (const float*)d_in[4];
    const int*   bl   = (const int*)d_in[5];
    const int*   bp   = (const int*)d_in[6];
    const int*   lm   = (const int*)d_in[7];
    const float* aW1  = (const float*)d_in[8];
    const float* ab1  = (const float*)d_in[9];
    const float* aW2  = (const float*)d_in[10];
    const float* ab2  = (const float*)d_in[11];
    const float* fW1  = (const float*)d_in[12];
    const float* fb1  = (const float*)d_in[13];
    const float* fW2  = (const float*)d_in[14];
    const float* fb2  = (const float*)d_in[15];
    const float* rW1  = (const float*)d_in[16];
    const float* rb1  = (const float*)d_in[17];
    const float* rW2  = (const float*)d_in[18];
    const float* rb2  = (const float*)d_in[19];
    const float* dW1  = (const float*)d_in[20];
    const float* db1  = (const float*)d_in[21];
    const float* dW2  = (const float*)d_in[22];
    const float* db2  = (const float*)d_in[23];
    const float* We   = (const float*)d_in[24];
    const float* be   = (const float*)d_in[25];
    const float* Wx   = (const float*)d_in[26];
    const float* bx   = (const float*)d_in[27];
    const float* Wh   = (const float*)d_in[28];
    const float* bh   = (const float*)d_in[29];

    float* ws  = (float*)d_ws;
    float* out = (float*)d_out;

    hipLaunchKernelGGL(encode_kernel, dim3((NTOT + 255) / 256), dim3(256), 0, stream,
                       xl, xp, posl, posp, t, bl, bp, lm,
                       aW1, ab1, aW2, ab2, fW1, fb1, fW2, fb2,
                       rW1, rb1, rW2, rb2, We, be, ws);

    hipLaunchKernelGGL(pair_kernel, dim3(NLIG * 64 / 256), dim3(256), 0, stream,
                       We, Wx, bx, ws);

    hipLaunchKernelGGL(decode_kernel, dim3((NLIG + 255) / 256), dim3(256), 0, stream,
                       lm, Wh, bh, dW1, db1, dW2, db2, ws, out);
}